// Round 10
// baseline (43358.075 us; speedup 1.0000x reference)
//
#include <hip/hip_runtime.h>

#define NWG   128
#define NTHR  512
#define TT    2048
#define HH    2048
#define EE    1024

__device__ __forceinline__ float wred(float v){
  v += __shfl_xor(v, 1, 64);
  v += __shfl_xor(v, 2, 64);
  v += __shfl_xor(v, 4, 64);
  v += __shfl_xor(v, 8, 64);
  v += __shfl_xor(v, 16, 64);
  v += __shfl_xor(v, 32, 64);
  return v;
}

__device__ __forceinline__ float sigm(float x){ return 1.0f / (1.0f + __expf(-x)); }

extern "C" __global__ void __launch_bounds__(NTHR, 1)
lstm_seq_kernel(const float* __restrict__ h0, const float* __restrict__ c0,
                const float* __restrict__ gt, const int* __restrict__ ugt,
                const float* __restrict__ W_emb, const float* __restrict__ b_emb,
                const float* __restrict__ W_ih, const float* __restrict__ b_ih,
                const float* __restrict__ W_hh, const float* __restrict__ b_hh,
                const float* __restrict__ W_out, const float* __restrict__ b_out,
                float* __restrict__ out, unsigned long long* __restrict__ hbuf)
{
  const int wgid = blockIdx.x;    // 0..127, owns hidden units [16*wgid, 16*wgid+16)
  const int tid  = threadIdx.x;
  const int gw   = tid >> 6;      // wave 0..7 owns units uA=j0+2gw, uA+1 (ALL 4 gates)
  const int l    = tid & 63;
  const int j0   = wgid * 16;
  const int uA   = j0 + 2*gw;

  __shared__ float h_lds[2][HH];  // double-buffered staging

  // ---------- setup: W_hh rows for this wave's 2 units x 4 gates ----------
  // u = g*2 + b  (g: 0=i,1=f,2=g,3=o ; b: unit A/B), row = 2048*g + uA + b
  float2 whh[8][16];
  #pragma unroll
  for (int u = 0; u < 8; ++u){
    const float* rp = W_hh + (size_t)(2048*(u>>1) + uA + (u&1)) * HH;
    #pragma unroll
    for (int i = 0; i < 16; ++i)
      whh[u][i] = *(const float2*)(rp + 2*l + 128*i);
  }
  // W_out rows (redundant per wave -> no cross-wave exchange for raw)
  float2 wo0[16], wo1[16];
  #pragma unroll
  for (int i = 0; i < 16; ++i){
    wo0[i] = *(const float2*)(W_out + 2*l + 128*i);
    wo1[i] = *(const float2*)(W_out + HH + 2*l + 128*i);
  }
  const float bo0 = b_out[0], bo1 = b_out[1];

  // ---------- setup: E = W_ih@W_emb cols, B = W_ih@b_emb + b_ih + b_hh ----------
  float aE0[8], aE1[8], aB[8];
  #pragma unroll
  for (int u = 0; u < 8; ++u){ aE0[u] = 0.f; aE1[u] = 0.f; aB[u] = 0.f; }
  for (int i = 0; i < 16; ++i){
    const int k = l + 64*i;
    const float2 we = *(const float2*)(W_emb + 2*k);
    const float be = b_emb[k];
    #pragma unroll
    for (int u = 0; u < 8; ++u){
      const float wv = W_ih[(size_t)(2048*(u>>1) + uA + (u&1))*EE + k];
      aE0[u] = fmaf(wv, we.x, aE0[u]);
      aE1[u] = fmaf(wv, we.y, aE1[u]);
      aB[u]  = fmaf(wv, be,  aB[u]);
    }
  }
  float e0v[8], e1v[8], bv[8];
  #pragma unroll
  for (int u = 0; u < 8; ++u){
    const int r = 2048*(u>>1) + uA + (u&1);
    e0v[u] = wred(aE0[u]);
    e1v[u] = wred(aE1[u]);
    bv[u]  = wred(aB[u]) + b_ih[r] + b_hh[r];
  }

  float cA = c0[uA], cB = c0[uA + 1];   // all lanes hold both cell states

  for (int t = 0; t < TT; ++t){
    // ---- hoist gt/ugt (cached loads, overlap the poll) ----
    float g0 = 0.f, g1 = 0.f; int ug = 0;
    if (t > 0){
      g0 = gt[2*(t-1)]; g1 = gt[2*(t-1)+1]; ug = ugt[t-1];
    }

    // ---- poll tagged h_{t-1} (this wave's eighth: 4 entries/lane),
    //      only-stale reloads to keep LLC poll traffic at the straggler tail ----
    float* hl = h_lds[t & 1];
    const int e0i = (gw << 8) + l;
    if (t == 0){
      #pragma unroll
      for (int i = 0; i < 4; ++i)
        hl[e0i + (i<<6)] = h0[e0i + (i<<6)];
    } else {
      const unsigned long long* bp = hbuf + ((t-1)&1)*HH + e0i;
      const unsigned tagexp = (unsigned)t;
      unsigned fresh = 0; int rounds = 0;
      while (fresh != 0xFu){
        unsigned long long v[4];
        #pragma unroll
        for (int i = 0; i < 4; ++i)
          if (!(fresh & (1u<<i)))
            v[i] = __hip_atomic_load(bp + (i<<6), __ATOMIC_RELAXED, __HIP_MEMORY_SCOPE_AGENT);
        #pragma unroll
        for (int i = 0; i < 4; ++i){
          if (!(fresh & (1u<<i)) && (unsigned)(v[i] >> 32) == tagexp){
            hl[e0i + (i<<6)] = __uint_as_float((unsigned)v[i]);
            fresh |= (1u<<i);
          }
        }
        if (++rounds > 32768) break;           // anti-hang guard
      }
    }
    __syncthreads();   // the ONLY barrier per step

    // ---- dot products: 8 rows (2 units x 4 gates) + redundant W_out rows ----
    float ga[8];
    #pragma unroll
    for (int u = 0; u < 8; ++u) ga[u] = 0.f;
    float r0 = 0.f, r1 = 0.f;
    #pragma unroll
    for (int i = 0; i < 16; ++i){
      const float2 hv = *(const float2*)(hl + 2*l + 128*i);
      r0 = fmaf(wo0[i].x, hv.x, r0); r0 = fmaf(wo0[i].y, hv.y, r0);
      r1 = fmaf(wo1[i].x, hv.x, r1); r1 = fmaf(wo1[i].y, hv.y, r1);
      #pragma unroll
      for (int u = 0; u < 8; ++u){
        ga[u] = fmaf(whh[u][i].x, hv.x, ga[u]);
        ga[u] = fmaf(whh[u][i].y, hv.y, ga[u]);
      }
    }
    #pragma unroll
    for (int u = 0; u < 8; ++u) ga[u] = wred(ga[u]);   // sums land in ALL lanes
    r0 = wred(r0); r1 = wred(r1);

    // ---- raw_{t-1}, teacher forcing ----
    const float raw0 = r0 + bo0, raw1 = r1 + bo1;
    float n0, n1;
    if (t == 0){ n0 = 1.f; n1 = 1.f; }     // x0 = W_emb@ones(2)+b_emb  <=> nxt=(1,1)
    else {
      if (wgid == 0 && tid == 0){
        out[2*(t-1)]   = raw0;
        out[2*(t-1)+1] = raw1;
      }
      n0 = (ug == 1) ? g0 : raw0;
      n1 = (ug == 1) ? g1 : raw1;
    }

    // ---- gate finals + LSTM cells, wave-redundant in all lanes ----
    float gf[8];
    #pragma unroll
    for (int u = 0; u < 8; ++u)
      gf[u] = ga[u] + fmaf(e0v[u], n0, fmaf(e1v[u], n1, bv[u]));
    const float cAn = sigm(gf[2])*cA + sigm(gf[0])*tanhf(gf[4]);
    const float hA  = sigm(gf[6])*tanhf(cAn); cA = cAn;
    const float cBn = sigm(gf[3])*cB + sigm(gf[1])*tanhf(gf[5]);
    const float hB  = sigm(gf[7])*tanhf(cBn); cB = cBn;

    // ---- per-wave publish (2 tagged entries) ----
    if (l < 2){
      const float hv = (l == 0) ? hA : hB;
      const unsigned long long pk =
          ((unsigned long long)(unsigned)(t + 1) << 32) |
          (unsigned long long)__float_as_uint(hv);
      __hip_atomic_store(hbuf + (t&1)*HH + uA + l, pk, __ATOMIC_RELAXED, __HIP_MEMORY_SCOPE_AGENT);
    }
  }

  if (wgid != 0) return;

  // ---------- epilogue (WG0): raw for the final step ----------
  {
    float* hl = h_lds[0];
    const int e0i = (gw << 8) + l;
    const unsigned long long* bp = hbuf + ((TT-1)&1)*HH + e0i;
    const unsigned tagexp = (unsigned)TT;
    unsigned fresh = 0; int rounds = 0;
    while (fresh != 0xFu){
      unsigned long long v[4];
      #pragma unroll
      for (int i = 0; i < 4; ++i)
        if (!(fresh & (1u<<i)))
          v[i] = __hip_atomic_load(bp + (i<<6), __ATOMIC_RELAXED, __HIP_MEMORY_SCOPE_AGENT);
      #pragma unroll
      for (int i = 0; i < 4; ++i){
        if (!(fresh & (1u<<i)) && (unsigned)(v[i] >> 32) == tagexp){
          hl[e0i + (i<<6)] = __uint_as_float((unsigned)v[i]);
          fresh |= (1u<<i);
        }
      }
      if (++rounds > 32768) break;
    }
  }
  __syncthreads();
  if (gw == 0){
    const float* hl = h_lds[0];
    float r0 = 0.f, r1 = 0.f;
    #pragma unroll
    for (int i = 0; i < 16; ++i){
      const float2 hv = *(const float2*)(hl + 2*l + 128*i);
      r0 = fmaf(wo0[i].x, hv.x, r0); r0 = fmaf(wo0[i].y, hv.y, r0);
      r1 = fmaf(wo1[i].x, hv.x, r1); r1 = fmaf(wo1[i].y, hv.y, r1);
    }
    r0 = wred(r0); r1 = wred(r1);
    if (l == 0){
      out[2*(TT-1)]   = r0 + bo0;
      out[2*(TT-1)+1] = r1 + bo1;
    }
  }
}

// Loss = pure function of (preds, gt) — computed from the validated preds buffer.
extern "C" __global__ void loss_kernel(const float* __restrict__ preds,
                                       const float* __restrict__ gt,
                                       float* __restrict__ loss_out)
{
  const int tid = threadIdx.x;   // 256 threads, 8 steps each
  float acc = 0.f;
  #pragma unroll
  for (int s = 0; s < 8; ++s){
    const int t = tid + 256*s;
    const float d0 = preds[2*t]   - gt[2*t];
    const float d1 = preds[2*t+1] - gt[2*t+1];
    acc += 0.5f*(d0*d0 + d1*d1);
  }
  acc = wred(acc);
  __shared__ float ws[4];
  if ((tid & 63) == 0) ws[tid >> 6] = acc;
  __syncthreads();
  if (tid == 0) loss_out[0] = ws[0] + ws[1] + ws[2] + ws[3];
}

extern "C" void kernel_launch(void* const* d_in, const int* in_sizes, int n_in,
                              void* d_out, int out_size, void* d_ws, size_t ws_size,
                              hipStream_t stream)
{
  (void)in_sizes; (void)n_in; (void)out_size; (void)ws_size;
  const float* h0    = (const float*)d_in[0];
  const float* c0    = (const float*)d_in[1];
  const float* gt    = (const float*)d_in[2];
  const int*   ugt   = (const int*)  d_in[3];
  const float* W_emb = (const float*)d_in[4];
  const float* b_emb = (const float*)d_in[5];
  const float* W_ih  = (const float*)d_in[6];
  const float* b_ih  = (const float*)d_in[7];
  const float* W_hh  = (const float*)d_in[8];
  const float* b_hh  = (const float*)d_in[9];
  const float* W_out = (const float*)d_in[10];
  const float* b_out = (const float*)d_in[11];
  float* out  = (float*)d_out;
  unsigned long long* hbuf = (unsigned long long*)d_ws;   // 2 x 2048 tagged entries (32 KB)

  void* args[] = { &h0, &c0, &gt, &ugt, &W_emb, &b_emb, &W_ih, &b_ih,
                   &W_hh, &b_hh, &W_out, &b_out, &out, &hbuf };
  hipLaunchCooperativeKernel((const void*)lstm_seq_kernel,
                             dim3(NWG), dim3(NTHR), args, 0, stream);

  loss_kernel<<<dim3(1), dim3(256), 0, stream>>>(out, gt, out + 2*TT);
}

// Round 11
// 21881.433 us; speedup vs baseline: 1.9815x; 1.9815x over previous
//
#include <hip/hip_runtime.h>

#define NWG   256
#define NTHR  256
#define TT    2048
#define HH    2048
#define EE    1024

__device__ __forceinline__ float wred(float v){
  v += __shfl_xor(v, 1, 64);
  v += __shfl_xor(v, 2, 64);
  v += __shfl_xor(v, 4, 64);
  v += __shfl_xor(v, 8, 64);
  v += __shfl_xor(v, 16, 64);
  v += __shfl_xor(v, 32, 64);
  return v;
}

__device__ __forceinline__ float sigm(float x){ return 1.0f / (1.0f + __expf(-x)); }

extern "C" __global__ void __launch_bounds__(NTHR, 1)
lstm_seq_kernel(const float* __restrict__ h0, const float* __restrict__ c0,
                const float* __restrict__ gt, const int* __restrict__ ugt,
                const float* __restrict__ W_emb, const float* __restrict__ b_emb,
                const float* __restrict__ W_ih, const float* __restrict__ b_ih,
                const float* __restrict__ W_hh, const float* __restrict__ b_hh,
                const float* __restrict__ W_out, const float* __restrict__ b_out,
                float* __restrict__ out, unsigned long long* __restrict__ hbuf)
{
  const int wgid = blockIdx.x;    // 0..255, owns units [8*wgid, 8*wgid+8)
  const int tid  = threadIdx.x;
  const int gw   = tid >> 6;      // wave owns units uA=j0+2gw, uA+1 (ALL 4 gates)
  const int l    = tid & 63;
  const int j0   = wgid * 8;
  const int uA   = j0 + 2*gw;

  // ---------- setup: W_hh rows for this wave's 2 units x 4 gates ----------
  // u = g*2 + b (g: 0=i,1=f,2=g,3=o ; b: unit A/B), row = 2048*g + uA + b
  // lane l holds columns k = 2l+128i (+1), i = 0..15
  float2 whh[8][16];
  #pragma unroll
  for (int u = 0; u < 8; ++u){
    const float* rp = W_hh + (size_t)(2048*(u>>1) + uA + (u&1)) * HH;
    #pragma unroll
    for (int i = 0; i < 16; ++i)
      whh[u][i] = *(const float2*)(rp + 2*l + 128*i);
  }
  // W_out rows (redundant per wave)
  float2 wo0[16], wo1[16];
  #pragma unroll
  for (int i = 0; i < 16; ++i){
    wo0[i] = *(const float2*)(W_out + 2*l + 128*i);
    wo1[i] = *(const float2*)(W_out + HH + 2*l + 128*i);
  }
  const float bo0 = b_out[0], bo1 = b_out[1];

  // ---------- setup: E = W_ih@W_emb cols, B = W_ih@b_emb + b_ih + b_hh ----------
  float aE0[8], aE1[8], aB[8];
  #pragma unroll
  for (int u = 0; u < 8; ++u){ aE0[u] = 0.f; aE1[u] = 0.f; aB[u] = 0.f; }
  for (int i = 0; i < 16; ++i){
    const int k = l + 64*i;
    const float2 we = *(const float2*)(W_emb + 2*k);
    const float be = b_emb[k];
    #pragma unroll
    for (int u = 0; u < 8; ++u){
      const float wv = W_ih[(size_t)(2048*(u>>1) + uA + (u&1))*EE + k];
      aE0[u] = fmaf(wv, we.x, aE0[u]);
      aE1[u] = fmaf(wv, we.y, aE1[u]);
      aB[u]  = fmaf(wv, be,  aB[u]);
    }
  }
  float e0v[8], e1v[8], bv[8];
  #pragma unroll
  for (int u = 0; u < 8; ++u){
    const int r = 2048*(u>>1) + uA + (u&1);
    e0v[u] = wred(aE0[u]);
    e1v[u] = wred(aE1[u]);
    bv[u]  = wred(aB[u]) + b_ih[r] + b_hh[r];
  }

  float cA = c0[uA], cB = c0[uA + 1];   // all lanes hold both cell states

#define FMA_CHUNK(i, hv)                                              \
  do {                                                                \
    r0 = fmaf(wo0[i].x, (hv).x, r0); r0 = fmaf(wo0[i].y, (hv).y, r0); \
    r1 = fmaf(wo1[i].x, (hv).x, r1); r1 = fmaf(wo1[i].y, (hv).y, r1); \
    _Pragma("unroll")                                                 \
    for (int u = 0; u < 8; ++u){                                      \
      ga[u] = fmaf(whh[u][i].x, (hv).x, ga[u]);                       \
      ga[u] = fmaf(whh[u][i].y, (hv).y, ga[u]);                       \
    }                                                                 \
  } while (0)

  for (int t = 0; t < TT; ++t){
    // ---- hoist gt/ugt (cached loads, overlap the poll) ----
    float g0 = 0.f, g1 = 0.f; int ug = 0;
    if (t > 0){
      g0 = gt[2*(t-1)]; g1 = gt[2*(t-1)+1]; ug = ugt[t-1];
    }

    // ---- barrier-free: each lane polls exactly the h elements its FMAs use.
    // Chunk i = tagged entries {2l+128i, 2l+128i+1}; consume (FMA) on arrival.
    float ga[8];
    #pragma unroll
    for (int u = 0; u < 8; ++u) ga[u] = 0.f;
    float r0 = 0.f, r1 = 0.f;

    if (t == 0){
      #pragma unroll
      for (int i = 0; i < 16; ++i){
        const float2 hv = *(const float2*)(h0 + 2*l + 128*i);
        FMA_CHUNK(i, hv);
      }
    } else {
      const unsigned long long* bp = hbuf + ((t-1)&1)*HH + 2*l;
      const unsigned tagexp = (unsigned)t;
      unsigned pend = 0xFFFFu;
      int rounds = 0;
      while (pend){
        #pragma unroll
        for (int h8 = 0; h8 < 2; ++h8){        // two 8-chunk batches (bounds VGPRs)
          unsigned long long va[8], vb[8];
          #pragma unroll
          for (int j = 0; j < 8; ++j){
            const int i = h8*8 + j;
            if (pend & (1u<<i)){
              va[j] = __hip_atomic_load(bp + 128*i,     __ATOMIC_RELAXED, __HIP_MEMORY_SCOPE_AGENT);
              vb[j] = __hip_atomic_load(bp + 128*i + 1, __ATOMIC_RELAXED, __HIP_MEMORY_SCOPE_AGENT);
            }
          }
          #pragma unroll
          for (int j = 0; j < 8; ++j){
            const int i = h8*8 + j;
            if ((pend & (1u<<i)) &&
                (unsigned)(va[j] >> 32) == tagexp && (unsigned)(vb[j] >> 32) == tagexp){
              float2 hv;
              hv.x = __uint_as_float((unsigned)va[j]);
              hv.y = __uint_as_float((unsigned)vb[j]);
              FMA_CHUNK(i, hv);
              pend &= ~(1u<<i);
            }
          }
        }
        if (++rounds > 32768) break;           // anti-hang guard
      }
    }

    #pragma unroll
    for (int u = 0; u < 8; ++u) ga[u] = wred(ga[u]);   // sums land in ALL lanes
    r0 = wred(r0); r1 = wred(r1);

    // ---- raw_{t-1}, teacher forcing ----
    const float raw0 = r0 + bo0, raw1 = r1 + bo1;
    float n0, n1;
    if (t == 0){ n0 = 1.f; n1 = 1.f; }     // x0 = W_emb@ones(2)+b_emb <=> nxt=(1,1)
    else {
      if (wgid == 0 && tid == 0){
        out[2*(t-1)]   = raw0;
        out[2*(t-1)+1] = raw1;
      }
      n0 = (ug == 1) ? g0 : raw0;
      n1 = (ug == 1) ? g1 : raw1;
    }

    // ---- gate finals + LSTM cells, wave-redundant ----
    float gf[8];
    #pragma unroll
    for (int u = 0; u < 8; ++u)
      gf[u] = ga[u] + fmaf(e0v[u], n0, fmaf(e1v[u], n1, bv[u]));
    const float cAn = sigm(gf[2])*cA + sigm(gf[0])*tanhf(gf[4]);
    const float hA  = sigm(gf[6])*tanhf(cAn); cA = cAn;
    const float cBn = sigm(gf[3])*cB + sigm(gf[1])*tanhf(gf[5]);
    const float hB  = sigm(gf[7])*tanhf(cBn); cB = cBn;

    // ---- per-wave publish (2 tagged entries); after all loads consumed ----
    if (l < 2){
      const float hv = (l == 0) ? hA : hB;
      const unsigned long long pk =
          ((unsigned long long)(unsigned)(t + 1) << 32) |
          (unsigned long long)__float_as_uint(hv);
      __hip_atomic_store(hbuf + (t&1)*HH + uA + l, pk, __ATOMIC_RELAXED, __HIP_MEMORY_SCOPE_AGENT);
    }
  }

  // ---------- epilogue (WG0 wave0): raw for the final step ----------
  if (wgid != 0) return;
  if (gw == 0){
    const unsigned long long* bp = hbuf + ((TT-1)&1)*HH + 2*l;
    const unsigned tagexp = (unsigned)TT;
    float r0 = 0.f, r1 = 0.f;
    unsigned pend = 0xFFFFu;
    int rounds = 0;
    while (pend){
      #pragma unroll
      for (int i = 0; i < 16; ++i){
        if (pend & (1u<<i)){
          const unsigned long long va = __hip_atomic_load(bp + 128*i,     __ATOMIC_RELAXED, __HIP_MEMORY_SCOPE_AGENT);
          const unsigned long long vb = __hip_atomic_load(bp + 128*i + 1, __ATOMIC_RELAXED, __HIP_MEMORY_SCOPE_AGENT);
          if ((unsigned)(va >> 32) == tagexp && (unsigned)(vb >> 32) == tagexp){
            const float hx = __uint_as_float((unsigned)va);
            const float hy = __uint_as_float((unsigned)vb);
            r0 = fmaf(wo0[i].x, hx, r0); r0 = fmaf(wo0[i].y, hy, r0);
            r1 = fmaf(wo1[i].x, hx, r1); r1 = fmaf(wo1[i].y, hy, r1);
            pend &= ~(1u<<i);
          }
        }
      }
      if (++rounds > 32768) break;
    }
    r0 = wred(r0); r1 = wred(r1);
    if (l == 0){
      out[2*(TT-1)]   = r0 + bo0;
      out[2*(TT-1)+1] = r1 + bo1;
    }
  }
#undef FMA_CHUNK
}

// Loss = pure function of (preds, gt) — computed from the validated preds buffer.
extern "C" __global__ void loss_kernel(const float* __restrict__ preds,
                                       const float* __restrict__ gt,
                                       float* __restrict__ loss_out)
{
  const int tid = threadIdx.x;   // 256 threads, 8 steps each
  float acc = 0.f;
  #pragma unroll
  for (int s = 0; s < 8; ++s){
    const int t = tid + 256*s;
    const float d0 = preds[2*t]   - gt[2*t];
    const float d1 = preds[2*t+1] - gt[2*t+1];
    acc += 0.5f*(d0*d0 + d1*d1);
  }
  acc = wred(acc);
  __shared__ float ws[4];
  if ((tid & 63) == 0) ws[tid >> 6] = acc;
  __syncthreads();
  if (tid == 0) loss_out[0] = ws[0] + ws[1] + ws[2] + ws[3];
}

extern "C" void kernel_launch(void* const* d_in, const int* in_sizes, int n_in,
                              void* d_out, int out_size, void* d_ws, size_t ws_size,
                              hipStream_t stream)
{
  (void)in_sizes; (void)n_in; (void)out_size; (void)ws_size;
  const float* h0    = (const float*)d_in[0];
  const float* c0    = (const float*)d_in[1];
  const float* gt    = (const float*)d_in[2];
  const int*   ugt   = (const int*)  d_in[3];
  const float* W_emb = (const float*)d_in[4];
  const float* b_emb = (const float*)d_in[5];
  const float* W_ih  = (const float*)d_in[6];
  const float* b_ih  = (const float*)d_in[7];
  const float* W_hh  = (const float*)d_in[8];
  const float* b_hh  = (const float*)d_in[9];
  const float* W_out = (const float*)d_in[10];
  const float* b_out = (const float*)d_in[11];
  float* out  = (float*)d_out;
  unsigned long long* hbuf = (unsigned long long*)d_ws;   // 2 x 2048 tagged entries (32 KB)

  void* args[] = { &h0, &c0, &gt, &ugt, &W_emb, &b_emb, &W_ih, &b_ih,
                   &W_hh, &b_hh, &W_out, &b_out, &out, &hbuf };
  hipLaunchCooperativeKernel((const void*)lstm_seq_kernel,
                             dim3(NWG), dim3(NTHR), args, 0, stream);

  loss_kernel<<<dim3(1), dim3(256), 0, stream>>>(out, gt, out + 2*TT);
}

// Round 13
// 10196.530 us; speedup vs baseline: 4.2522x; 2.1460x over previous
//
#include <hip/hip_runtime.h>

#define NWG   256
#define NTHR  256
#define TT    2048
#define HH    2048
#define EE    1024

__device__ __forceinline__ float wred(float v){
  v += __shfl_xor(v, 1, 64);
  v += __shfl_xor(v, 2, 64);
  v += __shfl_xor(v, 4, 64);
  v += __shfl_xor(v, 8, 64);
  v += __shfl_xor(v, 16, 64);
  v += __shfl_xor(v, 32, 64);
  return v;
}

__device__ __forceinline__ float sigm(float x){ return 1.0f / (1.0f + __expf(-x)); }

extern "C" __global__ void __launch_bounds__(NTHR, 1)
lstm_seq_kernel(const float* __restrict__ h0, const float* __restrict__ c0,
                const float* __restrict__ gt, const int* __restrict__ ugt,
                const float* __restrict__ W_emb, const float* __restrict__ b_emb,
                const float* __restrict__ W_ih, const float* __restrict__ b_ih,
                const float* __restrict__ W_hh, const float* __restrict__ b_hh,
                const float* __restrict__ W_out, const float* __restrict__ b_out,
                float* __restrict__ out, unsigned long long* __restrict__ hbuf)
{
  const int wgid = blockIdx.x;    // 0..255, owns hidden units [8*wgid, 8*wgid+8)
  const int tid  = threadIdx.x;
  const int gw   = tid >> 6;      // wave owns units uA=j0+2gw, uA+1 (ALL 4 gates)
  const int l    = tid & 63;
  const int j0   = wgid * 8;
  const int uA   = j0 + 2*gw;

  __shared__ float h_lds[2][HH];  // double-buffered: one barrier/step, waves may skew

  // ---------- setup: W_hh rows for this wave's 2 units x 4 gates ----------
  // u = g*2 + b  (g: 0=i,1=f,2=g,3=o ; b: 0=unit A, 1=unit B), row = 2048*g + uA + b
  float2 whh[8][16];
  #pragma unroll
  for (int u = 0; u < 8; ++u){
    const float* rp = W_hh + (size_t)(2048*(u>>1) + uA + (u&1)) * HH;
    #pragma unroll
    for (int i = 0; i < 16; ++i)
      whh[u][i] = *(const float2*)(rp + 2*l + 128*i);
  }
  // W_out rows (each wave keeps a copy -> redundant raw, no cross-wave exchange)
  float2 wo0[16], wo1[16];
  #pragma unroll
  for (int i = 0; i < 16; ++i){
    wo0[i] = *(const float2*)(W_out + 2*l + 128*i);
    wo1[i] = *(const float2*)(W_out + HH + 2*l + 128*i);
  }
  const float bo0 = b_out[0], bo1 = b_out[1];

  // ---------- setup: E = W_ih@W_emb cols, B = W_ih@b_emb + b_ih + b_hh ----------
  // Replicated in ALL lanes (wred broadcasts) so the cell can run wave-redundant.
  float aE0[8], aE1[8], aB[8];
  #pragma unroll
  for (int u = 0; u < 8; ++u){ aE0[u] = 0.f; aE1[u] = 0.f; aB[u] = 0.f; }
  for (int i = 0; i < 16; ++i){
    const int k = l + 64*i;
    const float2 we = *(const float2*)(W_emb + 2*k);
    const float be = b_emb[k];
    #pragma unroll
    for (int u = 0; u < 8; ++u){
      const float wv = W_ih[(size_t)(2048*(u>>1) + uA + (u&1))*EE + k];
      aE0[u] = fmaf(wv, we.x, aE0[u]);
      aE1[u] = fmaf(wv, we.y, aE1[u]);
      aB[u]  = fmaf(wv, be,  aB[u]);
    }
  }
  float e0v[8], e1v[8], bv[8];
  #pragma unroll
  for (int u = 0; u < 8; ++u){
    const int r = 2048*(u>>1) + uA + (u&1);
    e0v[u] = wred(aE0[u]);
    e1v[u] = wred(aE1[u]);
    bv[u]  = wred(aB[u]) + b_ih[r] + b_hh[r];
  }

  float cA = c0[uA], cB = c0[uA + 1];   // all lanes hold both cell states

  for (int t = 0; t < TT; ++t){
    // ---- hoist gt/ugt for this step (cached loads, overlap the poll) ----
    float g0 = 0.f, g1 = 0.f; int ug = 0;
    if (t > 0){
      g0 = gt[2*(t-1)]; g1 = gt[2*(t-1)+1]; ug = ugt[t-1];
    }

    // ---- poll tagged h_{t-1} and stage into LDS buffer t&1.
    //      ONLY-STALE reloads: round 1 loads all 8, later rounds touch just the
    //      straggler entries -> poll LLC traffic collapses to the tail. ----
    float* hl = h_lds[t & 1];
    const int e0i = (gw << 9) + l;              // this wave's quarter
    if (t == 0){
      #pragma unroll
      for (int i = 0; i < 8; ++i)
        hl[e0i + (i<<6)] = h0[e0i + (i<<6)];
    } else {
      const unsigned long long* bp = hbuf + ((t-1)&1)*HH + e0i;
      const unsigned tagexp = (unsigned)t;
      unsigned fresh = 0; int rounds = 0;
      while (fresh != 0xFFu){
        unsigned long long v[8];
        #pragma unroll
        for (int i = 0; i < 8; ++i)
          if (!(fresh & (1u<<i)))
            v[i] = __hip_atomic_load(bp + (i<<6), __ATOMIC_RELAXED, __HIP_MEMORY_SCOPE_AGENT);
        #pragma unroll
        for (int i = 0; i < 8; ++i){
          if (!(fresh & (1u<<i)) && (unsigned)(v[i] >> 32) == tagexp){
            hl[e0i + (i<<6)] = __uint_as_float((unsigned)v[i]);
            fresh |= (1u<<i);
          }
        }
        if (++rounds > 32768) break;           // anti-hang guard
      }
    }
    __syncthreads();   // the ONLY barrier per step (staging rendezvous)

    // ---- dot products: 8 rows (2 units x 4 gates) + redundant W_out rows ----
    float ga[8];
    #pragma unroll
    for (int u = 0; u < 8; ++u) ga[u] = 0.f;
    float r0 = 0.f, r1 = 0.f;
    #pragma unroll
    for (int i = 0; i < 16; ++i){
      const float2 hv = *(const float2*)(hl + 2*l + 128*i);
      r0 = fmaf(wo0[i].x, hv.x, r0); r0 = fmaf(wo0[i].y, hv.y, r0);
      r1 = fmaf(wo1[i].x, hv.x, r1); r1 = fmaf(wo1[i].y, hv.y, r1);
      #pragma unroll
      for (int u = 0; u < 8; ++u){
        ga[u] = fmaf(whh[u][i].x, hv.x, ga[u]);
        ga[u] = fmaf(whh[u][i].y, hv.y, ga[u]);
      }
    }
    #pragma unroll
    for (int u = 0; u < 8; ++u) ga[u] = wred(ga[u]);   // sums land in ALL lanes
    r0 = wred(r0); r1 = wred(r1);

    // ---- raw_{t-1}, teacher forcing ----
    const float raw0 = r0 + bo0, raw1 = r1 + bo1;
    float n0, n1;
    if (t == 0){ n0 = 1.f; n1 = 1.f; }     // x0 = W_emb@ones(2)+b_emb  <=> nxt=(1,1)
    else {
      if (wgid == 0 && tid == 0){
        out[2*(t-1)]   = raw0;
        out[2*(t-1)+1] = raw1;
      }
      n0 = (ug == 1) ? g0 : raw0;
      n1 = (ug == 1) ? g1 : raw1;
    }

    // ---- gate finals + LSTM cells, wave-redundant in all lanes ----
    float gf[8];
    #pragma unroll
    for (int u = 0; u < 8; ++u)
      gf[u] = ga[u] + fmaf(e0v[u], n0, fmaf(e1v[u], n1, bv[u]));
    const float cAn = sigm(gf[2])*cA + sigm(gf[0])*tanhf(gf[4]);
    const float hA  = sigm(gf[6])*tanhf(cAn); cA = cAn;
    const float cBn = sigm(gf[3])*cB + sigm(gf[1])*tanhf(gf[5]);
    const float hB  = sigm(gf[7])*tanhf(cBn); cB = cBn;

    // ---- per-wave publish (no second barrier, no wave0 bottleneck) ----
    if (l < 2){
      const float hv = (l == 0) ? hA : hB;
      const unsigned long long pk =
          ((unsigned long long)(unsigned)(t + 1) << 32) |
          (unsigned long long)__float_as_uint(hv);
      __hip_atomic_store(hbuf + (t&1)*HH + uA + l, pk, __ATOMIC_RELAXED, __HIP_MEMORY_SCOPE_AGENT);
    }
  }

  if (wgid != 0) return;

  // ---------- epilogue (WG0): raw for the final step ----------
  {
    float* hl = h_lds[0];
    const int e0i = (gw << 9) + l;
    const unsigned long long* bp = hbuf + ((TT-1)&1)*HH + e0i;
    const unsigned tagexp = (unsigned)TT;
    unsigned fresh = 0; int rounds = 0;
    while (fresh != 0xFFu){
      unsigned long long v[8];
      #pragma unroll
      for (int i = 0; i < 8; ++i)
        if (!(fresh & (1u<<i)))
          v[i] = __hip_atomic_load(bp + (i<<6), __ATOMIC_RELAXED, __HIP_MEMORY_SCOPE_AGENT);
      #pragma unroll
      for (int i = 0; i < 8; ++i){
        if (!(fresh & (1u<<i)) && (unsigned)(v[i] >> 32) == tagexp){
          hl[e0i + (i<<6)] = __uint_as_float((unsigned)v[i]);
          fresh |= (1u<<i);
        }
      }
      if (++rounds > 32768) break;
    }
  }
  __syncthreads();
  if (gw == 0){
    const float* hl = h_lds[0];
    float r0 = 0.f, r1 = 0.f;
    #pragma unroll
    for (int i = 0; i < 16; ++i){
      const float2 hv = *(const float2*)(hl + 2*l + 128*i);
      r0 = fmaf(wo0[i].x, hv.x, r0); r0 = fmaf(wo0[i].y, hv.y, r0);
      r1 = fmaf(wo1[i].x, hv.x, r1); r1 = fmaf(wo1[i].y, hv.y, r1);
    }
    r0 = wred(r0); r1 = wred(r1);
    if (l == 0){
      out[2*(TT-1)]   = r0 + bo0;
      out[2*(TT-1)+1] = r1 + bo1;
    }
  }
}

// Loss = pure function of (preds, gt) — computed from the validated preds buffer.
extern "C" __global__ void loss_kernel(const float* __restrict__ preds,
                                       const float* __restrict__ gt,
                                       float* __restrict__ loss_out)
{
  const int tid = threadIdx.x;   // 256 threads, 8 steps each
  float acc = 0.f;
  #pragma unroll
  for (int s = 0; s < 8; ++s){
    const int t = tid + 256*s;
    const float d0 = preds[2*t]   - gt[2*t];
    const float d1 = preds[2*t+1] - gt[2*t+1];
    acc += 0.5f*(d0*d0 + d1*d1);
  }
  acc = wred(acc);
  __shared__ float ws[4];
  if ((tid & 63) == 0) ws[tid >> 6] = acc;
  __syncthreads();
  if (tid == 0) loss_out[0] = ws[0] + ws[1] + ws[2] + ws[3];
}

extern "C" void kernel_launch(void* const* d_in, const int* in_sizes, int n_in,
                              void* d_out, int out_size, void* d_ws, size_t ws_size,
                              hipStream_t stream)
{
  (void)in_sizes; (void)n_in; (void)out_size; (void)ws_size;
  const float* h0    = (const float*)d_in[0];
  const float* c0    = (const float*)d_in[1];
  const float* gt    = (const float*)d_in[2];
  const int*   ugt   = (const int*)  d_in[3];
  const float* W_emb = (const float*)d_in[4];
  const float* b_emb = (const float*)d_in[5];
  const float* W_ih  = (const float*)d_in[6];
  const float* b_ih  = (const float*)d_in[7];
  const float* W_hh  = (const float*)d_in[8];
  const float* b_hh  = (const float*)d_in[9];
  const float* W_out = (const float*)d_in[10];
  const float* b_out = (const float*)d_in[11];
  float* out  = (float*)d_out;
  unsigned long long* hbuf = (unsigned long long*)d_ws;   // 2 x 2048 tagged entries (32 KB)

  void* args[] = { &h0, &c0, &gt, &ugt, &W_emb, &b_emb, &W_ih, &b_ih,
                   &W_hh, &b_hh, &W_out, &b_out, &out, &hbuf };
  hipLaunchCooperativeKernel((const void*)lstm_seq_kernel,
                             dim3(NWG), dim3(NTHR), args, 0, stream);

  loss_kernel<<<dim3(1), dim3(256), 0, stream>>>(out, gt, out + 2*TT);
}

// Round 14
// 9191.241 us; speedup vs baseline: 4.7173x; 1.1094x over previous
//
#include <hip/hip_runtime.h>

#define NWG   256
#define NTHR  256
#define TT    2048
#define HH    2048
#define EE    1024

__device__ __forceinline__ float wred(float v){
  v += __shfl_xor(v, 1, 64);
  v += __shfl_xor(v, 2, 64);
  v += __shfl_xor(v, 4, 64);
  v += __shfl_xor(v, 8, 64);
  v += __shfl_xor(v, 16, 64);
  v += __shfl_xor(v, 32, 64);
  return v;
}

__device__ __forceinline__ float sigm(float x){ return 1.0f / (1.0f + __expf(-x)); }

extern "C" __global__ void __launch_bounds__(NTHR, 1)
lstm_seq_kernel(const float* __restrict__ h0, const float* __restrict__ c0,
                const float* __restrict__ gt, const int* __restrict__ ugt,
                const float* __restrict__ W_emb, const float* __restrict__ b_emb,
                const float* __restrict__ W_ih, const float* __restrict__ b_ih,
                const float* __restrict__ W_hh, const float* __restrict__ b_hh,
                const float* __restrict__ W_out, const float* __restrict__ b_out,
                float* __restrict__ out, unsigned long long* __restrict__ hbuf)
{
  const int wgid = blockIdx.x;    // 0..255, owns hidden units [8*wgid, 8*wgid+8)
  const int tid  = threadIdx.x;
  const int gw   = tid >> 6;      // wave owns units uA=j0+2gw, uA+1 (ALL 4 gates)
  const int l    = tid & 63;
  const int j0   = wgid * 8;
  const int uA   = j0 + 2*gw;

  __shared__ float h_lds[2][HH];  // double-buffered: one barrier/step

  // ---------- setup: W_hh rows for this wave's 2 units x 4 gates ----------
  // u = g*2 + b  (g: 0=i,1=f,2=g,3=o ; b: unit A/B), row = 2048*g + uA + b
  float2 whh[8][16];
  #pragma unroll
  for (int u = 0; u < 8; ++u){
    const float* rp = W_hh + (size_t)(2048*(u>>1) + uA + (u&1)) * HH;
    #pragma unroll
    for (int i = 0; i < 16; ++i)
      whh[u][i] = *(const float2*)(rp + 2*l + 128*i);
  }
  // W_out rows (each wave keeps a copy -> redundant raw, no cross-wave exchange)
  float2 wo0[16], wo1[16];
  #pragma unroll
  for (int i = 0; i < 16; ++i){
    wo0[i] = *(const float2*)(W_out + 2*l + 128*i);
    wo1[i] = *(const float2*)(W_out + HH + 2*l + 128*i);
  }
  const float bo0 = b_out[0], bo1 = b_out[1];

  // ---------- setup: E = W_ih@W_emb cols, B = W_ih@b_emb + b_ih + b_hh ----------
  float aE0[8], aE1[8], aB[8];
  #pragma unroll
  for (int u = 0; u < 8; ++u){ aE0[u] = 0.f; aE1[u] = 0.f; aB[u] = 0.f; }
  for (int i = 0; i < 16; ++i){
    const int k = l + 64*i;
    const float2 we = *(const float2*)(W_emb + 2*k);
    const float be = b_emb[k];
    #pragma unroll
    for (int u = 0; u < 8; ++u){
      const float wv = W_ih[(size_t)(2048*(u>>1) + uA + (u&1))*EE + k];
      aE0[u] = fmaf(wv, we.x, aE0[u]);
      aE1[u] = fmaf(wv, we.y, aE1[u]);
      aB[u]  = fmaf(wv, be,  aB[u]);
    }
  }
  float e0v[8], e1v[8], bv[8];
  #pragma unroll
  for (int u = 0; u < 8; ++u){
    const int r = 2048*(u>>1) + uA + (u&1);
    e0v[u] = wred(aE0[u]);
    e1v[u] = wred(aE1[u]);
    bv[u]  = wred(aB[u]) + b_ih[r] + b_hh[r];
  }

  float cA = c0[uA], cB = c0[uA + 1];   // all lanes hold both cell states

  for (int t = 0; t < TT; ++t){
    // ---- hoist gt/ugt for this step (cached loads, overlap the poll) ----
    float g0 = 0.f, g1 = 0.f; int ug = 0;
    if (t > 0){
      g0 = gt[2*(t-1)]; g1 = gt[2*(t-1)+1]; ug = ugt[t-1];
    }

    // ---- poll tagged h_{t-1}, stage into LDS buffer t&1 (R9 unconditional
    //      batched poll: 8 loads in flight, per-element vmcnt by compiler) ----
    float* hl = h_lds[t & 1];
    const int e0i = (gw << 9) + l;              // this wave's quarter
    if (t == 0){
      #pragma unroll
      for (int i = 0; i < 8; ++i)
        hl[e0i + (i<<6)] = h0[e0i + (i<<6)];
    } else {
      const unsigned long long* bp = hbuf + ((t-1)&1)*HH + e0i;
      const unsigned tagexp = (unsigned)t;
      unsigned fresh = 0; int rounds = 0;
      while (fresh != 0xFFu){
        unsigned long long v[8];
        #pragma unroll
        for (int i = 0; i < 8; ++i)
          v[i] = __hip_atomic_load(bp + (i<<6), __ATOMIC_RELAXED, __HIP_MEMORY_SCOPE_AGENT);
        #pragma unroll
        for (int i = 0; i < 8; ++i){
          if (!(fresh & (1u<<i)) && (unsigned)(v[i] >> 32) == tagexp){
            hl[e0i + (i<<6)] = __uint_as_float((unsigned)v[i]);
            fresh |= (1u<<i);
          }
        }
        if (++rounds > 32768) break;           // anti-hang guard
      }
    }
    __syncthreads();   // the ONLY barrier per step (staging rendezvous)

    // ---- dot products: 8 rows (2 units x 4 gates) + redundant W_out rows ----
    float ga[8];
    #pragma unroll
    for (int u = 0; u < 8; ++u) ga[u] = 0.f;
    float r0 = 0.f, r1 = 0.f;
    #pragma unroll
    for (int i = 0; i < 16; ++i){
      const float2 hv = *(const float2*)(hl + 2*l + 128*i);
      r0 = fmaf(wo0[i].x, hv.x, r0); r0 = fmaf(wo0[i].y, hv.y, r0);
      r1 = fmaf(wo1[i].x, hv.x, r1); r1 = fmaf(wo1[i].y, hv.y, r1);
      #pragma unroll
      for (int u = 0; u < 8; ++u){
        ga[u] = fmaf(whh[u][i].x, hv.x, ga[u]);
        ga[u] = fmaf(whh[u][i].y, hv.y, ga[u]);
      }
    }
    // ga wreds FIRST: the publish path depends only on these (+n0/n1).
    #pragma unroll
    for (int u = 0; u < 8; ++u) ga[u] = wred(ga[u]);   // sums land in ALL lanes

    const bool forced = (t == 0) || (ug == 1);   // wave-uniform branch
    if (forced){
      // ---- FAST PATH: n0/n1 known without raw -> cell+publish immediately ----
      const float n0 = (t == 0) ? 1.f : g0;
      const float n1 = (t == 0) ? 1.f : g1;
      float gf[8];
      #pragma unroll
      for (int u = 0; u < 8; ++u)
        gf[u] = ga[u] + fmaf(e0v[u], n0, fmaf(e1v[u], n1, bv[u]));
      const float cAn = sigm(gf[2])*cA + sigm(gf[0])*tanhf(gf[4]);
      const float hA  = sigm(gf[6])*tanhf(cAn); cA = cAn;
      const float cBn = sigm(gf[3])*cB + sigm(gf[1])*tanhf(gf[5]);
      const float hB  = sigm(gf[7])*tanhf(cBn); cB = cBn;
      if (l < 2){
        const float hv = (l == 0) ? hA : hB;
        const unsigned long long pk =
            ((unsigned long long)(unsigned)(t + 1) << 32) |
            (unsigned long long)__float_as_uint(hv);
        __hip_atomic_store(hbuf + (t&1)*HH + uA + l, pk, __ATOMIC_RELAXED, __HIP_MEMORY_SCOPE_AGENT);
      }
      // deferred: raw + distributed out store (off critical path)
      if (t > 0 && wgid == ((t-1) & 255) && tid == 0){
        r0 = wred(r0); r1 = wred(r1);
        out[2*(t-1)]   = r0 + bo0;
        out[2*(t-1)+1] = r1 + bo1;
      }
    } else {
      // ---- SLOW PATH: need raw for teacher-forcing select ----
      r0 = wred(r0); r1 = wred(r1);
      const float raw0 = r0 + bo0, raw1 = r1 + bo1;
      float gf[8];
      #pragma unroll
      for (int u = 0; u < 8; ++u)
        gf[u] = ga[u] + fmaf(e0v[u], raw0, fmaf(e1v[u], raw1, bv[u]));
      const float cAn = sigm(gf[2])*cA + sigm(gf[0])*tanhf(gf[4]);
      const float hA  = sigm(gf[6])*tanhf(cAn); cA = cAn;
      const float cBn = sigm(gf[3])*cB + sigm(gf[1])*tanhf(gf[5]);
      const float hB  = sigm(gf[7])*tanhf(cBn); cB = cBn;
      if (l < 2){
        const float hv = (l == 0) ? hA : hB;
        const unsigned long long pk =
            ((unsigned long long)(unsigned)(t + 1) << 32) |
            (unsigned long long)__float_as_uint(hv);
        __hip_atomic_store(hbuf + (t&1)*HH + uA + l, pk, __ATOMIC_RELAXED, __HIP_MEMORY_SCOPE_AGENT);
      }
      if (wgid == ((t-1) & 255) && tid == 0){
        out[2*(t-1)]   = raw0;
        out[2*(t-1)+1] = raw1;
      }
    }
  }

  if (wgid != 0) return;

  // ---------- epilogue (WG0): raw for the final step ----------
  {
    float* hl = h_lds[0];
    const int e0i = (gw << 9) + l;
    const unsigned long long* bp = hbuf + ((TT-1)&1)*HH + e0i;
    const unsigned tagexp = (unsigned)TT;
    unsigned fresh = 0; int rounds = 0;
    while (fresh != 0xFFu){
      unsigned long long v[8];
      #pragma unroll
      for (int i = 0; i < 8; ++i)
        v[i] = __hip_atomic_load(bp + (i<<6), __ATOMIC_RELAXED, __HIP_MEMORY_SCOPE_AGENT);
      #pragma unroll
      for (int i = 0; i < 8; ++i){
        if (!(fresh & (1u<<i)) && (unsigned)(v[i] >> 32) == tagexp){
          hl[e0i + (i<<6)] = __uint_as_float((unsigned)v[i]);
          fresh |= (1u<<i);
        }
      }
      if (++rounds > 32768) break;
    }
  }
  __syncthreads();
  if (gw == 0){
    const float* hl = h_lds[0];
    float r0 = 0.f, r1 = 0.f;
    #pragma unroll
    for (int i = 0; i < 16; ++i){
      const float2 hv = *(const float2*)(hl + 2*l + 128*i);
      r0 = fmaf(wo0[i].x, hv.x, r0); r0 = fmaf(wo0[i].y, hv.y, r0);
      r1 = fmaf(wo1[i].x, hv.x, r1); r1 = fmaf(wo1[i].y, hv.y, r1);
    }
    r0 = wred(r0); r1 = wred(r1);
    if (l == 0){
      out[2*(TT-1)]   = r0 + bo0;
      out[2*(TT-1)+1] = r1 + bo1;
    }
  }
}

// Loss = pure function of (preds, gt) — computed from the validated preds buffer.
extern "C" __global__ void loss_kernel(const float* __restrict__ preds,
                                       const float* __restrict__ gt,
                                       float* __restrict__ loss_out)
{
  const int tid = threadIdx.x;   // 256 threads, 8 steps each
  float acc = 0.f;
  #pragma unroll
  for (int s = 0; s < 8; ++s){
    const int t = tid + 256*s;
    const float d0 = preds[2*t]   - gt[2*t];
    const float d1 = preds[2*t+1] - gt[2*t+1];
    acc += 0.5f*(d0*d0 + d1*d1);
  }
  acc = wred(acc);
  __shared__ float ws[4];
  if ((tid & 63) == 0) ws[tid >> 6] = acc;
  __syncthreads();
  if (tid == 0) loss_out[0] = ws[0] + ws[1] + ws[2] + ws[3];
}

extern "C" void kernel_launch(void* const* d_in, const int* in_sizes, int n_in,
                              void* d_out, int out_size, void* d_ws, size_t ws_size,
                              hipStream_t stream)
{
  (void)in_sizes; (void)n_in; (void)out_size; (void)ws_size;
  const float* h0    = (const float*)d_in[0];
  const float* c0    = (const float*)d_in[1];
  const float* gt    = (const float*)d_in[2];
  const int*   ugt   = (const int*)  d_in[3];
  const float* W_emb = (const float*)d_in[4];
  const float* b_emb = (const float*)d_in[5];
  const float* W_ih  = (const float*)d_in[6];
  const float* b_ih  = (const float*)d_in[7];
  const float* W_hh  = (const float*)d_in[8];
  const float* b_hh  = (const float*)d_in[9];
  const float* W_out = (const float*)d_in[10];
  const float* b_out = (const float*)d_in[11];
  float* out  = (float*)d_out;
  unsigned long long* hbuf = (unsigned long long*)d_ws;   // 2 x 2048 tagged entries (32 KB)

  void* args[] = { &h0, &c0, &gt, &ugt, &W_emb, &b_emb, &W_ih, &b_ih,
                   &W_hh, &b_hh, &W_out, &b_out, &out, &hbuf };
  hipLaunchCooperativeKernel((const void*)lstm_seq_kernel,
                             dim3(NWG), dim3(NTHR), args, 0, stream);

  loss_kernel<<<dim3(1), dim3(256), 0, stream>>>(out, gt, out + 2*TT);
}